// Round 7
// baseline (3774.453 us; speedup 1.0000x reference)
//
#include <hip/hip_runtime.h>
#include <cmath>

// ---------------------------------------------------------------------------
// RPN head on MI355X. fp32 throughout; conv FMA chain order (ic,ky,kx asc,
// fmaf(w,x,acc)) and the head's 16x16 two-level reduction are bit-exact vs
// the np reference (absmax 0.0 through R12) — preserve both exactly.
//
// R13 = R12 + register software-pipeline of W (1 ky-stage deep, A/B sets).
// History:
//   R6 (3277): W global + 9x im2col X. 68 VGPR, 3 blk/CU, VALU 59%.
//   R7 FAILED: reg cap below demand -> acc spill (10.4GB scratch).
//   R8 WORSE (3370): fewer barriers, same convoy. Not the fix.
//   R9 (3210): W LDS-prefetch 1 ic ahead: per-wave eff +50% (VALU 62 @
//     22% occ) but +50 regs -> 2 blk/CU ate it. Mechanism proven.
//   R10 FAILED (6.2ms): (256,3) cap 2 regs under demand -> hot-loop spill.
//   R11 (3100): W transient-from-L2 + X halo LDS. 68 VGPR, 3 blk/CU.
//   R12 (3125, neutral): barrier-free main loop + padded epilogue.
//     Conflicts 7.0e7->4.5e7 but time flat -> neither barriers nor bank
//     conflicts are the bottleneck. Remaining stall: per-ky serial
//     load->wait->FMA (duty ~55%, 3 waves can't cover).
// R13 change: two named W register sets (A/B). Each stage issues the NEXT
// (ic,ky) 6xfloat4 loads and FMAs the CURRENT set (resident ~384cy ->
// vmcnt wait ~0). Cross-ic wrap keeps the pipe full. 2-ic unrolled body
// (6 stages) makes A/B and X-buffer parity compile-time (no runtime reg
// indexing). asm "memory" fences at stage boundaries stop multi-set load
// hoisting (R5 spill mode). ~150-160 total regs -> still 3 blk/CU,
// NO launch-bounds cap (worst case occupancy drop, never a spill).
// Tripwires: WRITE_SIZE >> 27MB = spill; Occupancy < 25 = reg regress.
// ---------------------------------------------------------------------------

#define NTOT_PER_IMG 261888   // sum of H*W*3 over levels
#define ATOT_PER_IMG 4768     // 4*1000 + 768

__constant__ int c_NLVL[5] = {196608, 49152, 12288, 3072, 768};
__constant__ int c_KLVL[5] = {1000, 1000, 1000, 1000, 768};
__constant__ int c_LOFF[5] = {0, 196608, 245760, 258048, 261120};
__constant__ int c_AOFF[5] = {0, 1000, 2000, 3000, 4000};

struct Anch { float cx1[3]; float cy1[3]; };
struct ConvCfg { Anch an[5]; };

// In-wave LDS ordering fence (prologue only; in-wave ds ops execute in
// order on CDNA so the steady-state loop needs no explicit fence).
__device__ __forceinline__ void ldsWaveFence() {
  asm volatile("s_waitcnt lgkmcnt(0)" ::: "memory");
}

// One (ic,ky) FMA block: 3 kx groups, chain order (kx asc, i asc, p asc) —
// identical operand values and order to all previous rounds (bit-exact).
__device__ __forceinline__ void fma_block(
    float acc[8][8],
    const float4& w0, const float4& w1, const float4& w2,
    const float4& w3, const float4& w4, const float4& w5,
    const float4& xA, const float4& xB, const float2& xC) {
  float xw[10] = {xA.x, xA.y, xA.z, xA.w,
                  xB.x, xB.y, xB.z, xB.w, xC.x, xC.y};
  {
    float wv[8] = {w0.x, w0.y, w0.z, w0.w, w1.x, w1.y, w1.z, w1.w};
#pragma unroll
    for (int i = 0; i < 8; i++)
#pragma unroll
      for (int p = 0; p < 8; p++)
        acc[i][p] = __builtin_fmaf(wv[i], xw[p + 0], acc[i][p]);
  }
  {
    float wv[8] = {w2.x, w2.y, w2.z, w2.w, w3.x, w3.y, w3.z, w3.w};
#pragma unroll
    for (int i = 0; i < 8; i++)
#pragma unroll
      for (int p = 0; p < 8; p++)
        acc[i][p] = __builtin_fmaf(wv[i], xw[p + 1], acc[i][p]);
  }
  {
    float wv[8] = {w4.x, w4.y, w4.z, w4.w, w5.x, w5.y, w5.z, w5.w};
#pragma unroll
    for (int i = 0; i < 8; i++)
#pragma unroll
      for (int p = 0; p < 8; p++)
        acc[i][p] = __builtin_fmaf(wv[i], xw[p + 2], acc[i][p]);
  }
}

// Stage: fence (pins load groups to their slot), issue NEXT W set (6x
// float4), read current X row, FMA current W set. The fence stops the
// compiler from hoisting >1 future load-set into flight (reg blowup).
#define STAGE(C0, C1, C2, C3, C4, C5, N0, N1, N2, N3, N4, N5, nbase, xrow) \
  do {                                                                     \
    asm volatile("" ::: "memory");                                         \
    const float* nb_ = (nbase);                                            \
    N0 = *(const float4*)(nb_);                                            \
    N1 = *(const float4*)(nb_ + 4);                                        \
    N2 = *(const float4*)(nb_ + 256);                                      \
    N3 = *(const float4*)(nb_ + 260);                                      \
    N4 = *(const float4*)(nb_ + 512);                                      \
    N5 = *(const float4*)(nb_ + 516);                                      \
    const float* xr_ = (xrow);                                             \
    float4 xA_ = *(const float4*)(xr_);                                    \
    float4 xB_ = *(const float4*)(xr_ + 4);                                \
    float2 xC_ = *(const float2*)(xr_ + 8);                                \
    fma_block(acc, C0, C1, C2, C3, C4, C5, xA_, xB_, xC_);                 \
  } while (0)

// ------------------------------ weight transpose ---------------------------
__global__ __launch_bounds__(256) void wtrans(const float* __restrict__ Wsrc,
                                              float* __restrict__ Wt) {
  __shared__ float T[16][17];
  int k0 = blockIdx.x * 16;   // 2304/16 = 144
  int o0 = blockIdx.y * 16;   // 256/16  = 16
  int i = threadIdx.x >> 4, j = threadIdx.x & 15;
  T[i][j] = Wsrc[(size_t)(o0 + i) * 2304 + (k0 + j)];
  __syncthreads();
  Wt[(size_t)(k0 + i) * 256 + (o0 + j)] = T[j][i];
}

// ------------------------------ fused conv (implicit GEMM) -----------------
// Block tiles: L0 [0,2048) L1 [2048,2560) L2 [2560,2688) L3 [2688,2720)
// L4 [2720,2728); 64 px per tile, all 256 oc per block.
// ncols = min(W,64), R = 64/ncols rows; X halo (R+2)x(ncols+2) per wave.
__global__ __launch_bounds__(256, 2) void conv_gemm(
    const float* __restrict__ f0, const float* __restrict__ f1,
    const float* __restrict__ f2, const float* __restrict__ f3,
    const float* __restrict__ f4, const float* __restrict__ Wt,
    const float* __restrict__ convb, const float* __restrict__ clsw,
    const float* __restrict__ clsb, const float* __restrict__ bboxw,
    const float* __restrict__ bboxb, float* __restrict__ scoresOut,
    float4* __restrict__ boxesOut, ConvCfg cfg) {
  // [0,4160) = epilogue t[16px][260]; [4160,7424) = 4 wave-private X dbufs.
  __shared__ __align__(16) float s_mem[7424];
  __shared__ float s_Red2[272];                // [16][17] head values
  float* const s_tl = s_mem;
  float* const s_xbase = s_mem + 4160;

  // ---- decode level / image / tile ----
  int b = blockIdx.x;
  const float* feat;
  int lvl, img, tile, H, logW, stride, lvlOff;
  if (b < 2048) {
    lvl = 0; feat = f0; H = 256; logW = 8; stride = 4; lvlOff = 0;
    img = b >> 10; tile = b & 1023;
  } else if (b < 2560) {
    lvl = 1; feat = f1; H = 128; logW = 7; stride = 8; lvlOff = 196608;
    int r = b - 2048; img = r >> 8; tile = r & 255;
  } else if (b < 2688) {
    lvl = 2; feat = f2; H = 64; logW = 6; stride = 16; lvlOff = 245760;
    int r = b - 2560; img = r >> 6; tile = r & 63;
  } else if (b < 2720) {
    lvl = 3; feat = f3; H = 32; logW = 5; stride = 32; lvlOff = 258048;
    int r = b - 2688; img = r >> 4; tile = r & 15;
  } else {
    lvl = 4; feat = f4; H = 16; logW = 4; stride = 64; lvlOff = 261120;
    int r = b - 2720; img = r >> 2; tile = r & 3;
  }
  const int W = H, HW = H * W;
  const int p0 = tile * 64;
  const float* fimg = feat + (size_t)img * 256 * HW;

  // tile geometry for the halo layout
  const int log2nc = (logW < 6) ? logW : 6;   // ncols = min(W, 64)
  const int ncols = 1 << log2nc;
  const int R = 64 >> log2nc;                 // rows covered by the tile
  const int py0 = p0 >> logW;                 // first image row of tile
  const int c_start = p0 & (W - 1);           // first image col of tile
  const int WIN = ncols + 2;                  // halo row width
  const int NX = (R + 2) * WIN;               // values staged per ic (<=198)

  const int tid = threadIdx.x;
  const int wid = tid >> 6;         // wave id 0..3
  const int lane = tid & 63;
  const int oc0 = (tid >> 3) * 8;   // 32 oc-groups x 8 oc
  const int pxg = tid & 7;          // 8 px-groups x 8 px
  const int px0 = pxg * 8;
  const int trow = px0 >> log2nc;          // thread's row within tile
  const int tcol0 = px0 & (ncols - 1);     // thread's first col within tile

  float* const buf0 = s_xbase + wid * 816;   // this wave's X dbuf (even ic)
  float* const buf1 = buf0 + 408;            // odd ic

  // ---- per-wave X staging descriptors (loop-invariant) ----
  int goffX[4], loffX[4];
#pragma unroll
  for (int s = 0; s < 4; s++) {
    int idx = lane + 64 * s;
    goffX[s] = -1; loffX[s] = -1;
    if (idx < NX) {
      int lr = idx / WIN;
      int lc = idx - lr * WIN;
      int sy = py0 - 1 + lr;
      int sx = c_start - 1 + lc;
      loffX[s] = lr * 68 + lc;   // row stride 68 floats
      if (sy >= 0 && sy < H && sx >= 0 && sx < W) goffX[s] = sy * W + sx;
    }
  }

  float acc[8][8];
#pragma unroll
  for (int i = 0; i < 8; i++)
#pragma unroll
    for (int p = 0; p < 8; p++) acc[i][p] = 0.f;

  // ---- prologue: stage ic=0 X halo into buf0; preload W(0,ky0) into A ----
#pragma unroll
  for (int s = 0; s < 4; s++)
    if (loffX[s] >= 0)
      buf0[loffX[s]] = (goffX[s] >= 0) ? fimg[goffX[s]] : 0.f;
  ldsWaveFence();

  float4 A0, A1, A2, A3, A4, A5, B0, B1, B2, B3, B4, B5;
  {
    const float* wb = Wt + oc0;
    A0 = *(const float4*)(wb);
    A1 = *(const float4*)(wb + 4);
    A2 = *(const float4*)(wb + 256);
    A3 = *(const float4*)(wb + 260);
    A4 = *(const float4*)(wb + 512);
    A5 = *(const float4*)(wb + 516);
  }

  const float* xr0 = buf0 + trow * 68 + tcol0;
  const float* xr1 = buf1 + trow * 68 + tcol0;

  // ---- main loop: 2 ics (6 pipelined stages) per iteration ----
#pragma unroll 1
  for (int icc = 0; icc < 128; icc++) {
    const int ic0 = icc * 2, ic1 = ic0 + 1;
    const int ic2 = (ic0 + 2 < 256) ? ic0 + 2 : 0;   // clamped wrap (tail)

    // issue ic1's X staging loads (consumed by the buf1 write after S1)
    float pxA[4];
    {
      const float* fp = fimg + (size_t)ic1 * HW;
#pragma unroll
      for (int s = 0; s < 4; s++)
        pxA[s] = (goffX[s] >= 0) ? fp[goffX[s]] : 0.f;
    }

    const float* w_ic0 = Wt + (size_t)ic0 * 2304 + oc0;
    const float* w_ic1 = w_ic0 + 2304;
    const float* w_ic2 = Wt + (size_t)ic2 * 2304 + oc0;

    // S1: FMA (ic0,ky0)=A, load B=W(ic0,ky1)
    STAGE(A0, A1, A2, A3, A4, A5, B0, B1, B2, B3, B4, B5,
          w_ic0 + 768, xr0);
    // write ic1's X into buf1 (in-wave ds order: visible to S4's reads)
#pragma unroll
    for (int s = 0; s < 4; s++)
      if (loffX[s] >= 0) buf1[loffX[s]] = pxA[s];

    // S2: FMA (ic0,ky1)=B, load A=W(ic0,ky2)
    STAGE(B0, B1, B2, B3, B4, B5, A0, A1, A2, A3, A4, A5,
          w_ic0 + 1536, xr0 + 68);

    // issue ic2's X staging loads (consumed by the buf0 write after S4)
    float pxB[4];
    {
      const float* fp = fimg + (size_t)ic2 * HW;
#pragma unroll
      for (int s = 0; s < 4; s++)
        pxB[s] = (goffX[s] >= 0) ? fp[goffX[s]] : 0.f;
    }

    // S3: FMA (ic0,ky2)=A, load B=W(ic1,ky0)
    STAGE(A0, A1, A2, A3, A4, A5, B0, B1, B2, B3, B4, B5,
          w_ic1, xr0 + 136);

    // S4: FMA (ic1,ky0)=B, load A=W(ic1,ky1)
    STAGE(B0, B1, B2, B3, B4, B5, A0, A1, A2, A3, A4, A5,
          w_ic1 + 768, xr1);
    // write ic2's X into buf0 (buf0 reads finished at S3; in-wave order)
#pragma unroll
    for (int s = 0; s < 4; s++)
      if (loffX[s] >= 0) buf0[loffX[s]] = pxB[s];

    // S5: FMA (ic1,ky1)=A, load B=W(ic1,ky2)
    STAGE(A0, A1, A2, A3, A4, A5, B0, B1, B2, B3, B4, B5,
          w_ic1 + 1536, xr1 + 68);

    // S6: FMA (ic1,ky2)=B, load A=W(ic2,ky0) (clamped on last iter; unused)
    STAGE(B0, B1, B2, B3, B4, B5, A0, A1, A2, A3, A4, A5,
          w_ic2, xr1 + 136);
  }

  // ---- epilogue: 4 rounds of 16 px through s_tl (stride 260) ----
  float cb[8];
#pragma unroll
  for (int i = 0; i < 8; i++) cb[i] = convb[oc0 + i];

  const Anch an = cfg.an[lvl];
  const float BCLIP = (float)4.135166556742356;  // log(1000/16)
  const size_t obase = (size_t)img * NTOT_PER_IMG + lvlOff;

#pragma unroll 1
  for (int r = 0; r < 4; r++) {
    if ((pxg >> 1) == r) {   // this thread's 8 px lie in round r
      int pl = px0 - 16 * r; // 0 or 8
#pragma unroll
      for (int p = 0; p < 8; p++) {
        float4 v0 = make_float4(fmaxf(acc[0][p] + cb[0], 0.f),
                                fmaxf(acc[1][p] + cb[1], 0.f),
                                fmaxf(acc[2][p] + cb[2], 0.f),
                                fmaxf(acc[3][p] + cb[3], 0.f));
        float4 v1 = make_float4(fmaxf(acc[4][p] + cb[4], 0.f),
                                fmaxf(acc[5][p] + cb[5], 0.f),
                                fmaxf(acc[6][p] + cb[6], 0.f),
                                fmaxf(acc[7][p] + cb[7], 0.f));
        *(float4*)(s_tl + (pl + p) * 260 + oc0) = v0;
        *(float4*)(s_tl + (pl + p) * 260 + oc0 + 4) = v1;
      }
    }
    __syncthreads();

    // heads: per (px, c) dot over 256 oc in 16x16 two-level order
    if (tid < 240) {
      int px = tid / 15, c = tid - px * 15;
      const float* wr0 = (c < 3) ? (clsw + c * 256) : (bboxw + (c - 3) * 256);
      float bb = (c < 3) ? clsb[c] : bboxb[c - 3];
      const float* trow2 = &s_tl[px * 260];
      float tot = 0.f;
#pragma unroll
      for (int g = 0; g < 16; g++) {
        const float* wr = wr0 + g * 16;
        const float* tr = trow2 + g * 16;
        float s = 0.f;
#pragma unroll
        for (int i = 0; i < 16; i++) s += wr[i] * tr[i];
        tot += s;
      }
      s_Red2[px * 17 + c] = tot + bb;
    }
    __syncthreads();

    // decode: one (pixel, anchor) per thread
    if (tid < 48) {
      int px = tid / 3, a = tid - px * 3;
      int pxl = p0 + r * 16 + px;
      int gy = pxl >> logW, gx = pxl & (W - 1);
      float sc = s_Red2[px * 17 + a];
      float dxv = s_Red2[px * 17 + 3 + a * 4 + 0];
      float dyv = s_Red2[px * 17 + 3 + a * 4 + 1];
      float dwv = s_Red2[px * 17 + 3 + a * 4 + 2];
      float dhv = s_Red2[px * 17 + 3 + a * 4 + 3];
      float sx = (float)(gx * stride), sy = (float)(gy * stride);
      float x1 = __fadd_rn(sx, an.cx1[a]);
      float x2 = __fsub_rn(sx, an.cx1[a]);
      float y1 = __fadd_rn(sy, an.cy1[a]);
      float y2 = __fsub_rn(sy, an.cy1[a]);
      float wdt = __fadd_rn(__fsub_rn(x2, x1), 1.0f);
      float hgt = __fadd_rn(__fsub_rn(y2, y1), 1.0f);
      float ctx = __fadd_rn(x1, __fmul_rn(0.5f, wdt));
      float cty = __fadd_rn(y1, __fmul_rn(0.5f, hgt));
      float dw = fminf(dwv, BCLIP), dh = fminf(dhv, BCLIP);
      float pcx = __fadd_rn(__fmul_rn(dxv, wdt), ctx);
      float pcy = __fadd_rn(__fmul_rn(dyv, hgt), cty);
      float pw = __fmul_rn(expf(dw), wdt);
      float ph = __fmul_rn(expf(dh), hgt);
      float hw = __fmul_rn(0.5f, pw), hh = __fmul_rn(0.5f, ph);
      float bx1 = __fsub_rn(pcx, hw);
      float by1 = __fsub_rn(pcy, hh);
      float bx2 = __fsub_rn(__fadd_rn(pcx, hw), 1.0f);
      float by2 = __fsub_rn(__fadd_rn(pcy, hh), 1.0f);
      bx1 = fminf(fmaxf(bx1, 0.f), 1023.f);
      by1 = fminf(fmaxf(by1, 0.f), 1023.f);
      bx2 = fminf(fmaxf(bx2, 0.f), 1023.f);
      by2 = fminf(fmaxf(by2, 0.f), 1023.f);
      size_t o = obase + (size_t)pxl * 3 + a;
      scoresOut[o] = sc;
      boxesOut[o] = make_float4(bx1, by1, bx2, by2);
    }
    __syncthreads();
  }
}

// ------------------------------ top-k --------------------------------------
__device__ __forceinline__ unsigned fkey(float f) {
  unsigned b = __float_as_uint(f);
  return (b & 0x80000000u) ? ~b : (b | 0x80000000u);
}
__device__ __forceinline__ float funkey(unsigned u) {
  unsigned b = (u & 0x80000000u) ? (u & 0x7fffffffu) : ~u;
  return __uint_as_float(b);
}

// Exact lax.top_k: value desc, index asc on ties. Radix-select the threshold,
// bisect an index cut for boundary ties, bitonic-sort packed (key, ~idx).
template <bool FINAL>
__global__ __launch_bounds__(1024) void topk_kernel(
    const float* __restrict__ scoresIn, const float4* __restrict__ boxesIn,
    float* __restrict__ scoresOut, float4* __restrict__ boxesOut,
    float* __restrict__ finalOut) {
  __shared__ unsigned long long keys[1024];
  __shared__ unsigned hist[256];
  __shared__ unsigned s_comm[4];
  int lvl = 0, img, N, k;
  const float* src;
  const float4* bsrc;
  if (FINAL) {
    img = blockIdx.x; N = ATOT_PER_IMG; k = 1000;
    src = scoresIn + (size_t)img * ATOT_PER_IMG;
    bsrc = boxesIn + (size_t)img * ATOT_PER_IMG;
  } else {
    lvl = blockIdx.x; img = blockIdx.y;
    N = c_NLVL[lvl]; k = c_KLVL[lvl];
    src = scoresIn + (size_t)img * NTOT_PER_IMG + c_LOFF[lvl];
    bsrc = boxesIn + (size_t)img * NTOT_PER_IMG + c_LOFF[lvl];
  }
  const int tid = threadIdx.x;

  unsigned pref = 0, pmask = 0, krem = (unsigned)k, cntT = 0;
  for (int pass = 3; pass >= 0; pass--) {
    int shift = pass * 8;
    if (tid < 256) hist[tid] = 0;
    __syncthreads();
    for (int i = tid; i < N; i += 1024) {
      unsigned u = fkey(src[i]);
      if ((u & pmask) == pref) atomicAdd(&hist[(u >> shift) & 255], 1u);
    }
    __syncthreads();
    if (tid == 0) {
      unsigned cum = 0;
      for (int d = 255; d >= 0; d--) {
        unsigned c = hist[d];
        if (cum + c >= krem) {
          s_comm[0] = krem - cum; s_comm[1] = c; s_comm[2] = (unsigned)d;
          break;
        }
        cum += c;
      }
    }
    __syncthreads();
    krem = s_comm[0]; cntT = s_comm[1];
    pref |= s_comm[2] << shift;
    pmask |= 0xFFu << shift;
    __syncthreads();
  }
  const unsigned T = pref, r = krem;
  unsigned m = (unsigned)N;
  if (r < cntT) {  // boundary ties: smallest r indices among {u == T}
    unsigned lo = 0, hi = (unsigned)N;
    while (lo < hi) {
      unsigned mid = (lo + hi) >> 1;
      if (tid == 0) s_comm[3] = 0;
      __syncthreads();
      for (unsigned i = tid; i < mid; i += 1024)
        if (fkey(src[i]) == T) atomicAdd(&s_comm[3], 1u);
      __syncthreads();
      unsigned c = s_comm[3];
      __syncthreads();
      if (c >= r) hi = mid; else lo = mid + 1;
    }
    m = lo;
  }
  if (tid == 0) s_comm[3] = 0;
  __syncthreads();
  for (int i = tid; i < N; i += 1024) {
    unsigned u = fkey(src[i]);
    if (u > T || (u == T && (unsigned)i < m)) {
      unsigned p = atomicAdd(&s_comm[3], 1u);
      if (p < 1024)
        keys[p] = ((unsigned long long)u << 32) | (unsigned)(~(unsigned)i);
    }
  }
  __syncthreads();
  if (tid >= k) keys[tid] = 0ull;  // pad; sorts to the end
  __syncthreads();
  // bitonic sort, descending
  for (unsigned k2 = 2; k2 <= 1024; k2 <<= 1) {
    for (unsigned j = k2 >> 1; j > 0; j >>= 1) {
      unsigned i = tid, ixj = i ^ j;
      if (ixj > i) {
        unsigned long long a = keys[i], b = keys[ixj];
        bool sw = ((i & k2) == 0) ? (a < b) : (a > b);
        if (sw) { keys[i] = b; keys[ixj] = a; }
      }
      __syncthreads();
    }
  }
  if (tid < k) {
    unsigned long long key = keys[tid];
    unsigned u = (unsigned)(key >> 32);
    unsigned idx = ~((unsigned)key);
    float sc = funkey(u);
    float4 b = bsrc[idx];
    if (FINAL) {
      float* o = finalOut + ((size_t)img * 1000 + tid) * 5;
      o[0] = b.x; o[1] = b.y; o[2] = b.z; o[3] = b.w; o[4] = sc;
    } else {
      scoresOut[(size_t)img * ATOT_PER_IMG + c_AOFF[lvl] + tid] = sc;
      boxesOut[(size_t)img * ATOT_PER_IMG + c_AOFF[lvl] + tid] = b;
    }
  }
}

// ------------------------------ NMS ----------------------------------------
__global__ __launch_bounds__(256) void nms_matrix(
    const float4* __restrict__ allb, unsigned long long* __restrict__ supp) {
  int lvl = blockIdx.x, img = blockIdx.y, rb = blockIdx.z;
  int k = c_KLVL[lvl];
  int task = img * 5 + lvl;
  const float4* src = allb + (size_t)img * ATOT_PER_IMG + c_AOFF[lvl];
  __shared__ float4 bb[1000];
  __shared__ float ar[1000];
  for (int j = threadIdx.x; j < k; j += 256) {
    float4 b = src[j];
    bb[j] = b;
    ar[j] = __fmul_rn(__fsub_rn(b.z, b.x), __fsub_rn(b.w, b.y));
  }
  __syncthreads();
  int i = rb * 256 + threadIdx.x;
  if (i < k) {
    float4 bi = bb[i];
    float ai = ar[i];
    unsigned long long* row = supp + ((size_t)task * 1024 + i) * 16;
    int jw0 = i >> 6;
    for (int jw = 0; jw < jw0; jw++) row[jw] = 0ull;
    for (int jw = jw0; jw < 16; jw++) {
      unsigned long long bits = 0;
      int jbase = jw * 64;
      for (int jj = 0; jj < 64; jj++) {
        int j = jbase + jj;
        if (j > i && j < k) {
          float4 bj = bb[j];
          float ltx = fmaxf(bi.x, bj.x), lty = fmaxf(bi.y, bj.y);
          float rbx = fminf(bi.z, bj.z), rby = fminf(bi.w, bj.w);
          float wx = fmaxf(__fsub_rn(rbx, ltx), 0.f);
          float wy = fmaxf(__fsub_rn(rby, lty), 0.f);
          float inter = __fmul_rn(wx, wy);
          float den = __fadd_rn(__fsub_rn(__fadd_rn(ai, ar[j]), inter), 1e-9f);
          if (__fdiv_rn(inter, den) > 0.7f) bits |= 1ull << jj;
        }
      }
      row[jw] = bits;
    }
  }
}

__global__ __launch_bounds__(64) void nms_scan(
    const float* __restrict__ topS, const unsigned long long* __restrict__ supp,
    float* __restrict__ fscore) {
  int lvl = blockIdx.x, img = blockIdx.y;
  int k = c_KLVL[lvl];
  int task = img * 5 + lvl;
  int lane = threadIdx.x;
  const unsigned long long* base = supp + (size_t)task * 1024 * 16;
  unsigned long long rem = 0, keep = 0;  // lane l<16 holds 64-bit word l
  for (int b0 = 0; b0 < k; b0 += 16) {
    unsigned long long buf[16];
#pragma unroll
    for (int t = 0; t < 16; t++) {
      int i = b0 + t;
      buf[t] = (lane < 16 && i < k) ? base[(size_t)i * 16 + lane] : 0ull;
    }
#pragma unroll
    for (int t = 0; t < 16; t++) {
      int i = b0 + t;
      if (i >= k) break;
      int wi = i >> 6, bi = i & 63;
      unsigned long long rw = __shfl(rem, wi);
      if (!((rw >> bi) & 1ull)) {  // i survives: suppress its row
        rem |= buf[t];
        if (lane == wi) keep |= (1ull << bi);
      }
    }
  }
  const float* ts = topS + (size_t)img * ATOT_PER_IMG + c_AOFF[lvl];
  float* fs = fscore + (size_t)img * ATOT_PER_IMG + c_AOFF[lvl];
  for (int i = lane; i < k; i += 64) {
    int wi = i >> 6;
    unsigned long long kw = __shfl(keep, wi);
    fs[i] = ((kw >> (i & 63)) & 1ull) ? ts[i] : -1e9f;
  }
}

// ------------------------------ host ---------------------------------------
static Anch mkAnch(double size) {
  Anch a;
  const double R[3] = {0.5, 1.0, 2.0};
  for (int i = 0; i < 3; i++) {
    double w = size * sqrt(1.0 / R[i]);
    double h = size * sqrt(R[i]);
    a.cx1[i] = (float)(-w / 2.0);
    a.cy1[i] = (float)(-h / 2.0);
  }
  return a;
}

extern "C" void kernel_launch(void* const* d_in, const int* in_sizes, int n_in,
                              void* d_out, int out_size, void* d_ws,
                              size_t ws_size, hipStream_t stream) {
  (void)in_sizes; (void)n_in; (void)out_size; (void)ws_size;
  const float* f0 = (const float*)d_in[0];
  const float* f1 = (const float*)d_in[1];
  const float* f2 = (const float*)d_in[2];
  const float* f3 = (const float*)d_in[3];
  const float* f4 = (const float*)d_in[4];
  const float* conv_w = (const float*)d_in[5];
  const float* conv_b = (const float*)d_in[6];
  const float* cls_w  = (const float*)d_in[7];
  const float* cls_b  = (const float*)d_in[8];
  const float* bbox_w = (const float*)d_in[9];
  const float* bbox_b = (const float*)d_in[10];
  float* out = (float*)d_out;

  // workspace layout (floats), all 16B-aligned; total ~14.4 MB
  float* wsf = (float*)d_ws;
  float* Wt     = wsf;                      // 589824
  float* scores = Wt + 589824;              // 2*261888
  float* boxes  = scores + 2 * NTOT_PER_IMG;       // 2*261888*4
  float* topS   = boxes + (size_t)2 * NTOT_PER_IMG * 4;  // 2*4768
  float* allb   = topS + 2 * ATOT_PER_IMG;         // 2*4768*4
  float* fscore = allb + (size_t)2 * ATOT_PER_IMG * 4;   // 2*4768
  unsigned long long* supp =
      (unsigned long long*)(fscore + 2 * ATOT_PER_IMG);  // 10*1024*16 u64

  wtrans<<<dim3(144, 16), 256, 0, stream>>>(conv_w, Wt);

  ConvCfg cfg;
  const double SZ[5] = {32, 64, 128, 256, 512};
  for (int l = 0; l < 5; l++) cfg.an[l] = mkAnch(SZ[l]);

  conv_gemm<<<2728, 256, 0, stream>>>(f0, f1, f2, f3, f4, Wt, conv_b, cls_w,
                                      cls_b, bbox_w, bbox_b, scores,
                                      (float4*)boxes, cfg);

  topk_kernel<false><<<dim3(5, 2), 1024, 0, stream>>>(
      scores, (const float4*)boxes, topS, (float4*)allb, nullptr);
  nms_matrix<<<dim3(5, 2, 4), 256, 0, stream>>>((const float4*)allb, supp);
  nms_scan<<<dim3(5, 2), 64, 0, stream>>>(topS, supp, fscore);
  topk_kernel<true><<<2, 1024, 0, stream>>>(
      fscore, (const float4*)allb, nullptr, nullptr, out);
}